// Round 4
// baseline (555.572 us; speedup 1.0000x reference)
//
#include <hip/hip_runtime.h>

typedef __attribute__((ext_vector_type(4))) float floatx4;
typedef __attribute__((ext_vector_type(8))) short short8;

#define AS1(p) ((const __attribute__((address_space(1))) unsigned int*)(p))
#define AS3(p) ((__attribute__((address_space(3))) unsigned int*)(p))

static __device__ __forceinline__ void async16(const void* g, void* l) {
  __builtin_amdgcn_global_load_lds(AS1(g), AS3(l), 16, 0, 0);
}

static __device__ __forceinline__ unsigned short f2bf(float f) {
  unsigned u = __float_as_uint(f);
  unsigned r = u + 0x7FFFu + ((u >> 16) & 1u);
  return (unsigned short)(r >> 16);
}
static __device__ __forceinline__ unsigned packbf(float lo, float hi) {
  unsigned ul = __float_as_uint(lo), uh = __float_as_uint(hi);
  ul = ul + 0x7FFFu + ((ul >> 16) & 1u);
  uh = uh + 0x7FFFu + ((uh >> 16) & 1u);
  return (ul >> 16) | (uh & 0xFFFF0000u);
}
static __device__ __forceinline__ float bf2f(unsigned short h) {
  return __uint_as_float(((unsigned)h) << 16);
}
static __device__ __forceinline__ float bf_lo(unsigned u) { return __uint_as_float(u << 16); }
static __device__ __forceinline__ float bf_hi(unsigned u) { return __uint_as_float(u & 0xFFFF0000u); }

// ---------------------------------------------------------------- styles
__global__ void k_styles(const float* __restrict__ w, const float* __restrict__ aw,
                         const float* __restrict__ ab, float* __restrict__ styles) {
  int t = blockIdx.x * 256 + threadIdx.x;   // 4096
  int b = t >> 9, c = t & 511;
  float acc = 0.f;
  for (int d = 0; d < 512; ++d) acc += w[b * 512 + d] * aw[c * 512 + d];
  styles[t] = acc * 0.04419417382415922f + ab[c];
}

// ---------------------------------------------------------------- msr = rsqrt(mean(styles^2))
__global__ void k_msr(const float* __restrict__ styles, float* __restrict__ msr) {
  __shared__ float red[256];
  float acc = 0.f;
  for (int i = threadIdx.x; i < 4096; i += 256) { float v = styles[i]; acc += v * v; }
  red[threadIdx.x] = acc; __syncthreads();
  for (int s = 128; s > 0; s >>= 1) {
    if ((int)threadIdx.x < s) red[threadIdx.x] += red[threadIdx.x + s];
    __syncthreads();
  }
  if (threadIdx.x == 0) *msr = rsqrtf(red[0] / 4096.0f);
}

// ---------------------------------------------------------------- per-o weight stats
__global__ void k_wstat(const float* __restrict__ cw, float* __restrict__ t, float* __restrict__ q) {
  int o = blockIdx.x, tid = threadIdx.x;
  __shared__ float red[256];
  float tot = 0.f;
  for (int i = tid; i < 512; i += 256) {
    const float* p = cw + ((size_t)o * 512 + i) * 9;
    float s = 0.f;
#pragma unroll
    for (int k = 0; k < 9; ++k) s += p[k] * p[k];
    q[o * 512 + i] = s;
    tot += s;
  }
  red[tid] = tot; __syncthreads();
  for (int s2 = 128; s2 > 0; s2 >>= 1) {
    if (tid < s2) red[tid] += red[tid + s2];
    __syncthreads();
  }
  if (tid == 0) t[o] = rsqrtf(red[0] / 4608.0f);
}

// ---------------------------------------------------------------- g[b,o]
__global__ void k_dmod(const float* __restrict__ styles, const float* __restrict__ msr,
                       const float* __restrict__ t, const float* __restrict__ q,
                       float* __restrict__ g) {
  int idx = blockIdx.x * 256 + threadIdx.x;  // 4096
  int b = idx >> 9, o = idx & 511;
  float m = *msr;
  float acc = 0.f;
  for (int i = 0; i < 512; ++i) {
    float s = styles[b * 512 + i] * m;
    acc += s * s * q[o * 512 + i];
  }
  float to = t[o];
  g[idx] = to * rsqrtf(to * to * acc + 1e-8f);
}

// ---------------------------------------------------------------- wbf2: fragment-order packed bf16 weights
__global__ __launch_bounds__(256) void k_wpack(const float* __restrict__ cw,
                                               const float* __restrict__ styles,
                                               const float* __restrict__ msr,
                                               const float* __restrict__ g,
                                               unsigned short* __restrict__ wbf2) {
  __shared__ float raw[512][11];
  int o = blockIdx.x, tid = threadIdx.x;
  for (int i = tid; i < 512; i += 256) {
    const float* p = cw + ((size_t)o * 512 + i) * 9;
#pragma unroll
    for (int k = 0; k < 9; ++k) raw[i][k] = p[k];
  }
  __syncthreads();
  float m = *msr;
  const int nb = o >> 7, wn = (o >> 6) & 1, ni = (o >> 4) & 3, ol = o & 15;
  for (int b = 0; b < 8; ++b) {
    float gg = g[b * 512 + o];
    const size_t base_bo = ((size_t)(b * 4 + nb) * 2 + wn);
    for (int f = tid; f < 9 * 512; f += 256) {
      int s = f >> 9, i = f & 511;
      int ic = i >> 5, qq = (i >> 3) & 3, j = i & 7;
      float v = raw[i][s] * gg * (styles[b * 512 + i] * m);
      size_t idx = ((((base_bo * 9 + s) * 16 + ic) * 4 + ni) * 512) + (qq * 16 + ol) * 8 + j;
      wbf2[idx] = f2bf(v);
    }
  }
}

// ---------------------------------------------------------------- xp[b][Y][X][c] NHWC bf16 zero-padded (+2)
__global__ __launch_bounds__(256) void k_xpack(const float* __restrict__ x,
                                               unsigned short* __restrict__ xp) {
  __shared__ float tile[64][65];
  int Y = blockIdx.x, cc0 = blockIdx.y * 64, b = blockIdx.z;
  int tid = threadIdx.x;
  int yy = Y - 2;
  bool valid = (yy >= 0 && yy < 64);
  if (valid) {
    for (int it = 0; it < 16; ++it) {
      int f = it * 256 + tid;
      int cc = f >> 6, xx = f & 63;
      tile[xx][cc] = x[(((size_t)b * 512 + cc0 + cc) * 64 + yy) * 64 + xx];
    }
  }
  __syncthreads();
  for (int it = 0; it < 17; ++it) {
    int f = it * 256 + tid;   // < 68*64
    int X = f >> 6, cc = f & 63;
    int xx = X - 2;
    float v = (valid && xx >= 0 && xx < 64) ? tile[xx][cc] : 0.f;
    xp[(((size_t)b * 68 + Y) * 68 + X) * 512 + cc0 + cc] = f2bf(v);
  }
}

// ---------------------------------------------------------------- patch-based implicit-GEMM conv
// 64m x 128n tile, 4 blocks/CU (LDS 40960B). Patch: 4 rows x 80-padded vecs x 32ch,
// double-buffered. B: 2-deep register prefetch from wbf2 (L2-resident via XCD pinning).
// Per-ic raw barrier with vmcnt(8): leaves the 8 newest B loads in flight.
__global__ __launch_bounds__(256, 4) void k_conv(const unsigned short* __restrict__ xp,
                                                 const unsigned short* __restrict__ wbf2,
                                                 const float* __restrict__ cb,
                                                 float* __restrict__ y) {
  __shared__ __align__(16) unsigned short lds[20480];   // 40960 B: 2 x (4*80*32)
  const int tid = threadIdx.x;
  const int w = tid >> 6, lane = tid & 63;
  const int wm = w & 1, wn = w >> 1;
  const int q = lane >> 4, ln = lane & 15;

  // XCD pinning: batch b == XCD; within XCD, consecutive blocks share nt (B stripe L2-resident)
  const int b = blockIdx.x & 7;
  const int rest = blockIdx.x >> 3;        // 0..275
  const int nt = rest / 69;
  const int mt = rest - nt * 69;
  const int m0 = mt * 64, n0 = nt * 128;
  const int oy0 = m0 / 66;

  const unsigned short* xpb = xp + (size_t)b * (68 * 68 * 512);

  // staging: wave w stages patch row w (80 padded vecs = 5 async16)
  size_t gof_p[5];
  {
    int Y = oy0 + w; if (Y > 67) Y = 67;
#pragma unroll
    for (int i = 0; i < 5; ++i) {
      int col = i * 16 + (lane >> 2);
      int vpad = w * 80 + col;
      int X = col > 67 ? 67 : col;
      int csrc = (lane & 3) ^ ((vpad >> 1) & 3);   // chunk-XOR swizzle (writer side)
      gof_p[i] = (size_t)(Y * 68 + X) * 512 + csrc * 8;
    }
  }

  // A-frag pixel bases (patch-local, pitch 80)
  int pvA[2];
#pragma unroll
  for (int mi = 0; mi < 2; ++mi) {
    int p = m0 + wm * 32 + mi * 16 + ln; if (p > 4355) p = 4355;
    int oy = p / 66, ox = p - oy * 66;
    pvA[mi] = (oy - oy0) * 80 + ox;
  }

  const unsigned short* wB = wbf2 + (((size_t)(b * 4 + nt) * 2 + wn) * 294912) + (size_t)lane * 8;

  floatx4 acc[2][4];
#pragma unroll
  for (int i = 0; i < 2; ++i)
#pragma unroll
    for (int j = 0; j < 4; ++j) acc[i][j] = (floatx4){0.f, 0.f, 0.f, 0.f};

  unsigned short* pat0 = lds;
  unsigned short* pat1 = lds + 10240;

  // prologue: patch(ic=0) + B(0,0), B(0,1)
#pragma unroll
  for (int i = 0; i < 5; ++i)
    async16(xpb + gof_p[i], pat0 + (w * 80 + i * 16) * 32);

  short8 bA[4], bB[4];
#pragma unroll
  for (int ni = 0; ni < 4; ++ni) bA[ni] = *(const short8*)(wB + ni * 512);
#pragma unroll
  for (int ni = 0; ni < 4; ++ni) bB[ni] = *(const short8*)(wB + 16 * 2048 + ni * 512);

  for (int ic = 0; ic < 16; ++ic) {
    // drain staging (older) but leave the 8 newest B loads in flight
    asm volatile("s_waitcnt vmcnt(8)" ::: "memory");
    asm volatile("s_barrier" ::: "memory");
    const unsigned short* pb = (ic & 1) ? pat1 : pat0;
    unsigned short* pn = (ic & 1) ? pat0 : pat1;
    const size_t pchan = (size_t)(ic + 1) * 32;
    const int icn = ic < 15 ? ic + 1 : 15;
#pragma unroll
    for (int s = 0; s < 9; ++s) {
      if (s < 5 && ic < 15)
        async16(xpb + gof_p[s] + pchan, pn + (w * 80 + s * 16) * 32);
      // unconditional 2-ahead B prefetch (uniform count -> exactly 8 in flight at barrier)
      const int ss2 = (s <= 6) ? s + 2 : s - 7;
      const int ic2 = (s <= 6) ? ic : icn;
      const unsigned short* wBn = wB + ((size_t)(ss2 * 16 + ic2)) * 2048;
      short8 bC[4];
#pragma unroll
      for (int ni = 0; ni < 4; ++ni) bC[ni] = *(const short8*)(wBn + ni * 512);
      const int d = (s / 3) * 80 + (s % 3);
      short8 aF[2];
#pragma unroll
      for (int mi = 0; mi < 2; ++mi) {
        int pv = pvA[mi] + d;
        int off = pv * 32 + ((q ^ ((pv >> 1) & 3)) << 3);
        aF[mi] = *(const short8*)(pb + off);
      }
#pragma unroll
      for (int mi = 0; mi < 2; ++mi)
#pragma unroll
        for (int ni = 0; ni < 4; ++ni)
          acc[mi][ni] = __builtin_amdgcn_mfma_f32_16x16x32_bf16(aF[mi], bA[ni], acc[mi][ni], 0, 0, 0);
#pragma unroll
      for (int ni = 0; ni < 4; ++ni) { bA[ni] = bB[ni]; bB[ni] = bC[ni]; }
    }
  }

  // ---------------- epilogue: per-wave LDS slab transpose -> contiguous float4 stores.
  // Slabs live in pat0 bytes [0,18432) — disjoint from pat1 (last-read buffer), no barrier needed.
  float* slab = (float*)lds + w * 1152;   // 32 o-rows x 36 pitch
  const int pbase = m0 + wm * 32;
  float cbv[4];
#pragma unroll
  for (int ni = 0; ni < 4; ++ni) cbv[ni] = cb[n0 + wn * 64 + ni * 16 + ln];

#pragma unroll
  for (int pass = 0; pass < 2; ++pass) {
#pragma unroll
    for (int ni2 = 0; ni2 < 2; ++ni2) {
      const int ni = pass * 2 + ni2;
#pragma unroll
      for (int mi = 0; mi < 2; ++mi) {
        float4 v;
        v.x = acc[mi][ni][0] + cbv[ni];
        v.y = acc[mi][ni][1] + cbv[ni];
        v.z = acc[mi][ni][2] + cbv[ni];
        v.w = acc[mi][ni][3] + cbv[ni];
        *(float4*)&slab[(ni2 * 16 + ln) * 36 + mi * 16 + q * 4] = v;
      }
    }
    const int ol = lane >> 1;
    const int ph = (lane & 1) * 16;
    const int o = n0 + wn * 64 + pass * 32 + ol;
    float* dst = &y[((size_t)b * 512 + o) * 4356 + pbase + ph];
#pragma unroll
    for (int j = 0; j < 4; ++j) {
      const int p4 = pbase + ph + j * 4;
      if (p4 < 4356)
        *(float4*)(dst + j * 4) = *(const float4*)&slab[ol * 36 + ph + j * 4];
    }
  }
}

// ---------------------------------------------------------------- fused up/act/down, strip-vectorized
__global__ __launch_bounds__(256, 4) void k_updown(const float* __restrict__ yg,
                                                   const float* __restrict__ uf,
                                                   const float* __restrict__ df,
                                                   float* __restrict__ out) {
  __shared__ __align__(16) unsigned short zraw[138 * 88];
  __shared__ __align__(16) unsigned short t1buf[138 * 56];
  const int tid = threadIdx.x;
  const int plane = blockIdx.x >> 1;
  const int s = blockIdx.x & 1;
  const float* yp = yg + (size_t)plane * 4356;

  float fub[12], fuc[12], fdw[12];
#pragma unroll
  for (int i = 0; i < 12; ++i) {
    float u = uf[11 - i] * 2.0f;
    fub[i] = u;
    fuc[i] = u * 1.41421356237309515f;
    fdw[i] = df[11 - i];
  }

  float* ybuf = (float*)zraw;
  const int xoff = 32 * s - 4;
  for (int t = tid; t < 75 * 48; t += 256) {
    int row = t / 48, col = t - row * 48;
    int r = row - 4, x = xoff + col;
    float v = (r >= 0 && r < 66 && x >= 0 && x < 66) ? yp[r * 66 + x] : 0.f;
    ybuf[t] = v;
  }
  __syncthreads();

  for (int t = tid; t < 69 * 6; t += 256) {
    int v = t / 6, c = t - v * 6;
    float ae[8], ao[8];
#pragma unroll
    for (int e = 0; e < 8; ++e) { ae[e] = 0.f; ao[e] = 0.f; }
#pragma unroll
    for (int u = 0; u < 6; ++u) {
      const float* yr = &ybuf[(v + u) * 48 + 8 * c];
      float4 p0 = *(const float4*)yr;
      float4 p1 = *(const float4*)(yr + 4);
      float fe = fub[2 * u + 1], fo = fub[2 * u];
      ae[0] += p0.x * fe; ao[0] += p0.x * fo;
      ae[1] += p0.y * fe; ao[1] += p0.y * fo;
      ae[2] += p0.z * fe; ao[2] += p0.z * fo;
      ae[3] += p0.w * fe; ao[3] += p0.w * fo;
      ae[4] += p1.x * fe; ao[4] += p1.x * fo;
      ae[5] += p1.y * fe; ao[5] += p1.y * fo;
      ae[6] += p1.z * fe; ao[6] += p1.z * fo;
      ae[7] += p1.w * fe; ao[7] += p1.w * fo;
    }
    uint4 se, so;
    se.x = packbf(ae[0], ae[1]); se.y = packbf(ae[2], ae[3]);
    se.z = packbf(ae[4], ae[5]); se.w = packbf(ae[6], ae[7]);
    so.x = packbf(ao[0], ao[1]); so.y = packbf(ao[2], ao[3]);
    so.z = packbf(ao[4], ao[5]); so.w = packbf(ao[6], ao[7]);
    *(uint4*)&t1buf[(2 * v) * 56 + 8 * c] = se;
    *(uint4*)&t1buf[(2 * v + 1) * 56 + 8 * c] = so;
  }
  __syncthreads();

  for (int t = tid; t < 138 * 5; t += 256) {
    int Y = t / 5, k = t - Y * 5;
    const unsigned short* tr = &t1buf[Y * 56 + 8 * k];
    uint4 r0 = *(const uint4*)tr;
    uint4 r1 = *(const uint4*)(tr + 8);
    float a[14];
    a[0] = bf_lo(r0.x);  a[1] = bf_hi(r0.x);
    a[2] = bf_lo(r0.y);  a[3] = bf_hi(r0.y);
    a[4] = bf_lo(r0.z);  a[5] = bf_hi(r0.z);
    a[6] = bf_lo(r0.w);  a[7] = bf_hi(r0.w);
    a[8] = bf_lo(r1.x);  a[9] = bf_hi(r1.x);
    a[10] = bf_lo(r1.y); a[11] = bf_hi(r1.y);
    a[12] = bf_lo(r1.z); a[13] = bf_hi(r1.z);
    float ae[8], ao[8];
#pragma unroll
    for (int p = 0; p < 8; ++p) { ae[p] = 0.f; ao[p] = 0.f; }
#pragma unroll
    for (int u = 0; u < 6; ++u) {
      float fe = fuc[2 * u + 1], fo = fuc[2 * u];
#pragma unroll
      for (int p = 0; p < 8; ++p) {
        float tv = a[p + u];
        ae[p] += tv * fe;
        ao[p] += tv * fo;
      }
    }
    uint4 s0, s1;
    float ze[8], zo[8];
#pragma unroll
    for (int p = 0; p < 8; ++p) {
      float v0 = fmaxf(ae[p], 0.f) + 0.2f * fminf(ae[p], 0.f);
      float v1 = fmaxf(ao[p], 0.f) + 0.2f * fminf(ao[p], 0.f);
      ze[p] = fminf(fmaxf(v0, -256.f), 256.f);
      zo[p] = fminf(fmaxf(v1, -256.f), 256.f);
    }
    s0.x = packbf(ze[0], zo[0]); s0.y = packbf(ze[1], zo[1]);
    s0.z = packbf(ze[2], zo[2]); s0.w = packbf(ze[3], zo[3]);
    s1.x = packbf(ze[4], zo[4]); s1.y = packbf(ze[5], zo[5]);
    s1.z = packbf(ze[6], zo[6]); s1.w = packbf(ze[7], zo[7]);
    unsigned short* zr = &zraw[Y * 88 + 16 * k];
    *(uint4*)zr = s0;
    *(uint4*)(zr + 8) = s1;
  }
  __syncthreads();

  unsigned short* t2 = t1buf;
  for (int t = tid; t < 64 * 10; t += 256) {
    int yr = t / 10, k = t - yr * 10;
    float acc[8];
#pragma unroll
    for (int e = 0; e < 8; ++e) acc[e] = 0.f;
#pragma unroll
    for (int i = 0; i < 12; ++i) {
      uint4 zv = *(const uint4*)&zraw[(2 * yr + i) * 88 + 8 * k];
      float c = fdw[i];
      acc[0] += c * bf_lo(zv.x); acc[1] += c * bf_hi(zv.x);
      acc[2] += c * bf_lo(zv.y); acc[3] += c * bf_hi(zv.y);
      acc[4] += c * bf_lo(zv.z); acc[5] += c * bf_hi(zv.z);
      acc[6] += c * bf_lo(zv.w); acc[7] += c * bf_hi(zv.w);
    }
    uint4 st;
    st.x = packbf(acc[0], acc[1]); st.y = packbf(acc[2], acc[3]);
    st.z = packbf(acc[4], acc[5]); st.w = packbf(acc[6], acc[7]);
    *(uint4*)&t2[yr * 88 + 8 * k] = st;
  }
  __syncthreads();

  {
    int t = tid;
    int yr = t >> 2, ce = t & 3;
    const unsigned short* tr = &t2[yr * 88 + 16 * ce];
    uint4 q0 = *(const uint4*)tr;
    uint4 q1 = *(const uint4*)(tr + 8);
    uint4 q2 = *(const uint4*)(tr + 16);
    uint4 q3 = *(const uint4*)(tr + 24);
    float wv[26];
    wv[0] = bf_lo(q0.x);  wv[1] = bf_hi(q0.x);
    wv[2] = bf_lo(q0.y);  wv[3] = bf_hi(q0.y);
    wv[4] = bf_lo(q0.z);  wv[5] = bf_hi(q0.z);
    wv[6] = bf_lo(q0.w);  wv[7] = bf_hi(q0.w);
    wv[8] = bf_lo(q1.x);  wv[9] = bf_hi(q1.x);
    wv[10] = bf_lo(q1.y); wv[11] = bf_hi(q1.y);
    wv[12] = bf_lo(q1.z); wv[13] = bf_hi(q1.z);
    wv[14] = bf_lo(q1.w); wv[15] = bf_hi(q1.w);
    wv[16] = bf_lo(q2.x); wv[17] = bf_hi(q2.x);
    wv[18] = bf_lo(q2.y); wv[19] = bf_hi(q2.y);
    wv[20] = bf_lo(q2.z); wv[21] = bf_hi(q2.z);
    wv[22] = bf_lo(q2.w); wv[23] = bf_hi(q2.w);
    wv[24] = bf_lo(q3.x); wv[25] = bf_hi(q3.x);
    float ov[8];
#pragma unroll
    for (int e = 0; e < 8; ++e) {
      float acc = 0.f;
#pragma unroll
      for (int j = 0; j < 12; ++j) acc += fdw[j] * wv[2 * e + j];
      ov[e] = acc;
    }
    float* op = out + (size_t)plane * 4096 + yr * 64 + 32 * s + 8 * ce;
    *(float4*)op = (float4){ov[0], ov[1], ov[2], ov[3]};
    *(float4*)(op + 4) = (float4){ov[4], ov[5], ov[6], ov[7]};
  }
}

extern "C" void kernel_launch(void* const* d_in, const int* in_sizes, int n_in,
                              void* d_out, int out_size, void* d_ws, size_t ws_size,
                              hipStream_t stream) {
  const float* x  = (const float*)d_in[0];
  const float* w  = (const float*)d_in[1];
  const float* aw = (const float*)d_in[2];
  const float* ab = (const float*)d_in[3];
  const float* cw = (const float*)d_in[4];
  const float* cb = (const float*)d_in[5];
  const float* uf = (const float*)d_in[6];
  const float* df = (const float*)d_in[7];
  float* out = (float*)d_out;
  char* ws = (char*)d_ws;

  float* styles = (float*)(ws + 0);
  float* msr    = (float*)(ws + 16384);
  float* tbuf   = (float*)(ws + 16640);
  float* qbuf   = (float*)(ws + 18688);
  float* gbuf   = (float*)(ws + 1067264);
  unsigned short* xp   = (unsigned short*)(ws + 1083648);
  unsigned short* wbf2 = (unsigned short*)(ws + 38963456);
  float* yb            = (float*)(ws + 76712192);

  k_styles<<<16, 256, 0, stream>>>(w, aw, ab, styles);
  k_msr<<<1, 256, 0, stream>>>(styles, msr);
  k_wstat<<<512, 256, 0, stream>>>(cw, tbuf, qbuf);
  k_dmod<<<16, 256, 0, stream>>>(styles, msr, tbuf, qbuf, gbuf);
  k_wpack<<<512, 256, 0, stream>>>(cw, styles, msr, gbuf, wbf2);
  k_xpack<<<dim3(68, 8, 8), 256, 0, stream>>>(x, xp);
  k_conv<<<2208, 256, 0, stream>>>(xp, wbf2, cb, yb);
  k_updown<<<8192, 256, 0, stream>>>(yb, uf, df, out);
}